// Round 4
// baseline (430.524 us; speedup 1.0000x reference)
//
#include <hip/hip_runtime.h>
#include <math.h>

#define NK 1024          // number of knots
#define NB 2048          // acceleration buckets (records table = 32 KB LDS)

typedef float f32x4 __attribute__((ext_vector_type(4)));  // for nontemporal ld/st

// ws float layout:
//   [0 .. 1024]      sorted xp (1025 incl. +inf sentinel)
//   [1025]           lo   (min knot x)
//   [1026]           scale (NB / range)
//   [1027]           pad
//   [1028 .. 5123]   quads: 1024 x float4 {x[i], y[i], x[i+1], y[i+1]}
//   [5124 .. 13315]  records: 2048 x float4 {x1, y1, slope, tag}
//                    tag as int: <0 => pure bucket, >=0 => start index for scan
#define WS_QUAD_OFF 1028
#define WS_REC_OFF  5124

// Monotone bucket map — MUST be bit-identical between setup (knots) and main
// (queries): correctness needs  xp >= x  ==>  bucket(xp) >= bucket(x).
// __fsub_rn/__fmul_rn forbid contraction; trunc + clamp are monotone.
__device__ __forceinline__ int bucket_of(float x, float lo, float scale) {
    float t = __fmul_rn(__fsub_rn(x, lo), scale);
    int b = (int)t;
    b = b < 0 ? 0 : b;
    b = b > (NB - 1) ? (NB - 1) : b;
    return b;
}

__global__ __launch_bounds__(1024) void setup_kernel(
        const float* __restrict__ xp_in, const float* __restrict__ yp_in,
        float* __restrict__ wsf)
{
    __shared__ float2 kv[NK];
    __shared__ float2 kv2[NK];
    __shared__ int    hist[NB];
    __shared__ int    starts[NB];
    __shared__ int    iscan[NK];
    __shared__ float  red[NK];
    __shared__ int    flag;
    __shared__ float  s_lo, s_scale;

    const int t = threadIdx.x;
    float xv = xp_in[t];
    kv[t] = make_float2(xv, yp_in[t]);

    // min/max reduce over knot x
    red[t] = xv; __syncthreads();
    for (int s = 512; s > 0; s >>= 1) {
        if (t < s) red[t] = fminf(red[t], red[t + s]);
        __syncthreads();
    }
    if (t == 0) s_lo = red[0];
    __syncthreads();
    red[t] = xv; __syncthreads();
    for (int s = 512; s > 0; s >>= 1) {
        if (t < s) red[t] = fmaxf(red[t], red[t + s]);
        __syncthreads();
    }
    if (t == 0) {
        float range = red[0] - s_lo;
        s_scale = (range > 0.0f) ? ((float)NB / range) : 0.0f;
    }
    __syncthreads();
    const float lo = s_lo, scale = s_scale;

    // histogram of knot buckets
    for (int i = t; i < NB; i += 1024) hist[i] = 0;
    __syncthreads();
    const int bt = bucket_of(xv, lo, scale);
    atomicAdd(&hist[bt], 1);
    __syncthreads();

    // exclusive prefix sum over 2048 buckets (thread t owns slots 2t, 2t+1)
    int c0 = hist[2 * t], c1 = hist[2 * t + 1];
    int tot = c0 + c1;
    iscan[t] = tot; __syncthreads();
    for (int off = 1; off < NK; off <<= 1) {
        int v = (t >= off) ? iscan[t - off] : 0;
        __syncthreads();
        iscan[t] += v;
        __syncthreads();
    }
    int excl = iscan[t] - tot;
    starts[2 * t]     = excl;
    starts[2 * t + 1] = excl + c0;
    __syncthreads();

    // scatter into bucket order (hist reused as per-bucket cursor, then = count)
    for (int i = t; i < NB; i += 1024) hist[i] = 0;
    __syncthreads();
    int pos = starts[bt] + atomicAdd(&hist[bt], 1);
    kv2[pos] = kv[t];
    __syncthreads();

    // odd-even transposition cleanup until fully sorted (tiny displacements)
    for (;;) {
        if (t == 0) flag = 0;
        __syncthreads();
        if (t < NK / 2) {
            int i0 = 2 * t;
            float2 a = kv2[i0], b = kv2[i0 + 1];
            if (a.x > b.x) { kv2[i0] = b; kv2[i0 + 1] = a; flag = 1; }
        }
        __syncthreads();
        if (t < NK / 2 - 1) {
            int i0 = 2 * t + 1;
            float2 a = kv2[i0], b = kv2[i0 + 1];
            if (a.x > b.x) { kv2[i0] = b; kv2[i0 + 1] = a; flag = 1; }
        }
        __syncthreads();
        if (!flag) break;
    }

    // emit: sorted xp (+sentinel), meta, quads
    wsf[t] = kv2[t].x;
    if (t == 0) {
        wsf[NK]   = INFINITY;   // sentinel terminates the fallback scan
        wsf[1025] = lo;
        wsf[1026] = scale;
    }
    float2 cur = kv2[t];
    float2 nxt = kv2[(t == NK - 1) ? (NK - 1) : (t + 1)];
    float4* qg = (float4*)(wsf + WS_QUAD_OFF);
    qg[t] = make_float4(cur.x, cur.y, nxt.x, nxt.y);

    // emit: per-bucket direct records
    // pure bucket (no knot inside): for ALL x in it, searchsorted(x) == start_b
    //   (monotone map), and start_b in [1, NK-1] since bucket0/NB-1 hold
    //   xmin/xmax and are impure => no boundary clamp needed on the fast path.
    float4* rg = (float4*)(wsf + WS_REC_OFF);
    for (int b = t; b < NB; b += 1024) {
        int cnt = hist[b];
        int st  = starts[b];
        float4 rec;
        if (cnt == 0) {
            int hi = st < 1 ? 1 : (st > NK - 1 ? NK - 1 : st);
            float2 p1 = kv2[hi - 1];
            float2 p2 = kv2[hi];
            float slope = (p2.y - p1.y) / (p2.x - p1.x);
            rec = make_float4(p1.x, p1.y, slope, __int_as_float(-1));
        } else {
            rec = make_float4(0.0f, 0.0f, 0.0f, __int_as_float(st));
        }
        rg[b] = rec;
    }
}

__global__ __launch_bounds__(256, 5) void interp_kernel(
        const f32x4* __restrict__ xq, f32x4* __restrict__ out,
        const float* __restrict__ wsf, int n4)
{
    __shared__ float4 recs[NB];   // 32 KB -> 5 blocks/CU

    const int t = threadIdx.x;
    // uniform scalar params (s_load)
    const float lo    = wsf[1025];
    const float scale = wsf[1026];
    const float xp0   = wsf[0];
    const float xpN   = wsf[NK - 1];
    const float yp0   = wsf[WS_QUAD_OFF + 1];
    const float ypN   = wsf[WS_QUAD_OFF + 4 * (NK - 1) + 1];
    const float*  gsxp   = wsf;
    const float4* gquads = (const float4*)(wsf + WS_QUAD_OFF);

    const float4* rsrc = (const float4*)(wsf + WS_REC_OFF);
    for (int i = t; i < NB; i += 256) recs[i] = rsrc[i];
    __syncthreads();

    int idx = blockIdx.x * 256 + t;
    const int stride = gridDim.x * 256;
    for (int q = idx; q < n4; q += stride) {
        f32x4 xv = __builtin_nontemporal_load(&xq[q]);
        float xs[4] = {xv.x, xv.y, xv.z, xv.w};
        float rs[4];
#pragma unroll
        for (int c = 0; c < 4; ++c) {
            float x = xs[c];
            int b = bucket_of(x, lo, scale);
            float4 rec = recs[b];
            // fast path: one LDS b128 + fma (pure-bucket lanes)
            float res = fmaf(x - rec.x, rec.z, rec.y);
            int w = __float_as_int(rec.w);
            if (w >= 0) {
                // impure bucket: scan from lower bound via global (L1/L2-resident)
                int j = w;
                while (gsxp[j] < x) ++j;
                int hi = j < 1 ? 1 : (j > NK - 1 ? NK - 1 : j);
                float4 qd = gquads[hi - 1];     // {x1, y1, x2, y2}
                float r = __builtin_amdgcn_rcpf(qd.z - qd.x);
                res = qd.y + (x - qd.x) * (qd.w - qd.y) * r;
                res = (x <= xp0) ? yp0 : res;   // idx == 0
                res = (x >  xpN) ? ypN : res;   // idx == n
            }
            rs[c] = res;
        }
        f32x4 r4 = {rs[0], rs[1], rs[2], rs[3]};
        __builtin_nontemporal_store(r4, &out[q]);
    }
}

extern "C" void kernel_launch(void* const* d_in, const int* in_sizes, int n_in,
                              void* d_out, int out_size, void* d_ws, size_t ws_size,
                              hipStream_t stream)
{
    const float* x  = (const float*)d_in[0];
    const float* xp = (const float*)d_in[1];
    const float* yp = (const float*)d_in[2];
    float* out = (float*)d_out;
    float* wsf = (float*)d_ws;

    setup_kernel<<<1, 1024, 0, stream>>>(xp, yp, wsf);

    const int n4 = out_size / 4;   // 33,554,432 / 4
    interp_kernel<<<1280, 256, 0, stream>>>((const f32x4*)x, (f32x4*)out, wsf, n4);
}

// Round 5
// 253.183 us; speedup vs baseline: 1.7004x; 1.7004x over previous
//
#include <hip/hip_runtime.h>
#include <math.h>

#define NK 1024          // number of knots
#define NB 2048          // acceleration buckets

typedef float f32x4 __attribute__((ext_vector_type(4)));

// ws float layout:
//   [0 .. 1023]      sorted xp
//   [1024 .. 2047]   sorted yp
//   [2048] lo   [2049] scale
//   [2052 .. 10243]  recs: 2048 x float4 {x1, y1, slope(+s in low 10 bits), xk_or_inf}
#define WS_YS_OFF   1024
#define WS_META_OFF 2048
#define WS_REC_OFF  2052   // 16B-aligned (2052*4 = 8208, /16 = 513)

// Monotone bucket map — MUST be bit-identical between setup (knots) and main
// (queries): correctness needs  xp >= x  ==>  bucket(xp) >= bucket(x).
__device__ __forceinline__ int bucket_of(float x, float lo, float scale) {
    float t = __fmul_rn(__fsub_rn(x, lo), scale);
    int b = (int)t;
    b = b < 0 ? 0 : b;
    b = b > (NB - 1) ? (NB - 1) : b;
    return b;
}

__global__ __launch_bounds__(1024) void setup_kernel(
        const float* __restrict__ xp_in, const float* __restrict__ yp_in,
        float* __restrict__ wsf)
{
    __shared__ float2 kv[NK];
    __shared__ float2 kv2[NK];
    __shared__ int    hist[NB];
    __shared__ int    starts[NB];
    __shared__ int    iscan[NK];
    __shared__ float  red[NK];
    __shared__ int    flag;
    __shared__ float  s_lo, s_scale;

    const int t = threadIdx.x;
    float xv = xp_in[t];
    kv[t] = make_float2(xv, yp_in[t]);

    // min/max reduce over knot x
    red[t] = xv; __syncthreads();
    for (int s = 512; s > 0; s >>= 1) {
        if (t < s) red[t] = fminf(red[t], red[t + s]);
        __syncthreads();
    }
    if (t == 0) s_lo = red[0];
    __syncthreads();
    red[t] = xv; __syncthreads();
    for (int s = 512; s > 0; s >>= 1) {
        if (t < s) red[t] = fmaxf(red[t], red[t + s]);
        __syncthreads();
    }
    if (t == 0) {
        float range = red[0] - s_lo;
        s_scale = (range > 0.0f) ? ((float)NB / range) : 0.0f;
    }
    __syncthreads();
    const float lo = s_lo, scale = s_scale;

    // histogram of knot buckets
    for (int i = t; i < NB; i += 1024) hist[i] = 0;
    __syncthreads();
    const int bt = bucket_of(xv, lo, scale);
    atomicAdd(&hist[bt], 1);
    __syncthreads();

    // exclusive prefix sum over 2048 buckets (thread t owns slots 2t, 2t+1)
    int c0 = hist[2 * t], c1 = hist[2 * t + 1];
    int tot = c0 + c1;
    iscan[t] = tot; __syncthreads();
    for (int off = 1; off < NK; off <<= 1) {
        int v = (t >= off) ? iscan[t - off] : 0;
        __syncthreads();
        iscan[t] += v;
        __syncthreads();
    }
    int excl = iscan[t] - tot;
    starts[2 * t]     = excl;
    starts[2 * t + 1] = excl + c0;
    __syncthreads();

    // scatter into bucket order (hist reused as cursor; ends back at counts)
    for (int i = t; i < NB; i += 1024) hist[i] = 0;
    __syncthreads();
    int pos = starts[bt] + atomicAdd(&hist[bt], 1);
    kv2[pos] = kv[t];
    __syncthreads();

    // odd-even transposition cleanup until fully sorted (tiny displacements)
    for (;;) {
        if (t == 0) flag = 0;
        __syncthreads();
        if (t < NK / 2) {
            int i0 = 2 * t;
            float2 a = kv2[i0], b = kv2[i0 + 1];
            if (a.x > b.x) { kv2[i0] = b; kv2[i0 + 1] = a; flag = 1; }
        }
        __syncthreads();
        if (t < NK / 2 - 1) {
            int i0 = 2 * t + 1;
            float2 a = kv2[i0], b = kv2[i0 + 1];
            if (a.x > b.x) { kv2[i0] = b; kv2[i0 + 1] = a; flag = 1; }
        }
        __syncthreads();
        if (!flag) break;
    }

    // emit sorted arrays + meta
    wsf[t]             = kv2[t].x;
    wsf[WS_YS_OFF + t] = kv2[t].y;
    if (t == 0) { wsf[WS_META_OFF] = lo; wsf[WS_META_OFF + 1] = scale; }

    // emit per-bucket records
    //  pure (cnt==0):  segment (s-1,s) valid for ALL x in bucket; w = +inf
    //  impure:         segment (s-1,s) valid for x <= xk = kv2[s].x; w = xk
    //  s==0 (bucket 0, impure; or pure-left — can't happen): rec returns yp[0]
    //    via {x1=0, y1=yp0, slope=0}.
    //  s (scan start) is packed into the low 10 mantissa bits of slope
    //    (relative slope error <= 2^-13 -> y error ~5e-4, far under threshold).
    float4* rg = (float4*)(wsf + WS_REC_OFF);
    for (int b = t; b < NB; b += 1024) {
        int cnt = hist[b];
        int st  = starts[b];
        float x1, y1, slope, w;
        if (cnt == 0) {
            int hi = st < 1 ? 1 : (st > NK - 1 ? NK - 1 : st);
            float2 p1 = kv2[hi - 1], p2 = kv2[hi];
            x1 = p1.x; y1 = p1.y;
            slope = (p2.y - p1.y) / (p2.x - p1.x);
            w = INFINITY;
        } else {
            w = kv2[st].x;               // xk: first knot in bucket
            if (st == 0) { x1 = 0.0f; y1 = kv2[0].y; slope = 0.0f; }
            else {
                float2 p1 = kv2[st - 1], p2 = kv2[st];
                x1 = p1.x; y1 = p1.y;
                slope = (p2.y - p1.y) / (p2.x - p1.x);
            }
        }
        unsigned sb = (__float_as_uint(slope) & 0xFFFFFC00u) | ((unsigned)st & 1023u);
        rg[b] = make_float4(x1, y1, __uint_as_float(sb), w);
    }
}

__global__ __launch_bounds__(256, 4) void interp_kernel(
        const f32x4* __restrict__ xq, f32x4* __restrict__ out,
        const float* __restrict__ wsf, int n4)
{
    __shared__ float4 recs[NB];   // 32 KB
    __shared__ float  sxp[NK];    //  4 KB
    __shared__ float  ys[NK];     //  4 KB   -> 40960 B total, 4 blocks/CU

    const int t = threadIdx.x;
    const float lo    = wsf[WS_META_OFF];
    const float scale = wsf[WS_META_OFF + 1];
    const float xpN   = wsf[NK - 1];
    const float ypN   = wsf[WS_YS_OFF + NK - 1];

    const float4* rsrc = (const float4*)(wsf + WS_REC_OFF);
    for (int i = t; i < NB; i += 256) recs[i] = rsrc[i];
    for (int i = t; i < NK; i += 256) { sxp[i] = wsf[i]; ys[i] = wsf[WS_YS_OFF + i]; }
    __syncthreads();

    int idx = blockIdx.x * 256 + t;
    const int stride = gridDim.x * 256;
    for (int q = idx; q < n4; q += stride) {
        f32x4 xv = xq[q];
        float xs[4] = {xv.x, xv.y, xv.z, xv.w};
        float rs[4];
#pragma unroll
        for (int c = 0; c < 4; ++c) {
            float x = xs[c];
            int b = bucket_of(x, lo, scale);
            float4 rec = recs[b];
            // fast path (~79% of lanes): one LDS b128 + fma
            float res = fmaf(x - rec.x, rec.z, rec.y);
            if (x > rec.w) {
                // slow path, all in LDS: scan from packed start index
                int j = __float_as_int(rec.z) & 1023;
                while (j < NK && sxp[j] < x) ++j;
                int hi = j > NK - 1 ? NK - 1 : j;   // j >= 1 here (x > sxp[s])
                float x1 = sxp[hi - 1], x2 = sxp[hi];
                float y1 = ys[hi - 1],  y2 = ys[hi];
                float r = __builtin_amdgcn_rcpf(x2 - x1);
                res = y1 + (x - x1) * (y2 - y1) * r;
                res = (x > xpN) ? ypN : res;        // idx == n clamp
            }
            rs[c] = res;
        }
        f32x4 r4 = {rs[0], rs[1], rs[2], rs[3]};
        out[q] = r4;
    }
}

extern "C" void kernel_launch(void* const* d_in, const int* in_sizes, int n_in,
                              void* d_out, int out_size, void* d_ws, size_t ws_size,
                              hipStream_t stream)
{
    const float* x  = (const float*)d_in[0];
    const float* xp = (const float*)d_in[1];
    const float* yp = (const float*)d_in[2];
    float* out = (float*)d_out;
    float* wsf = (float*)d_ws;

    setup_kernel<<<1, 1024, 0, stream>>>(xp, yp, wsf);

    const int n4 = out_size / 4;   // 8,388,608 float4
    // 1024 blocks = 4 blocks/CU x 256 CUs; 32 iterations/thread
    interp_kernel<<<1024, 256, 0, stream>>>((const f32x4*)x, (f32x4*)out, wsf, n4);
}